// Round 12
// baseline (249.523 us; speedup 1.0000x reference)
//
#include <hip/hip_runtime.h>
#include <float.h>
#include <math.h>

#define N_PTS 8192
#define NPAIR 4096        // candidate pairs
#define NB    256         // blocks (1 per CU)
#define NT    1024        // 16 waves/block -> 4 waves/SIMD
#define QPB   32          // queries per block
#define QPT   8           // queries per thread group
#define NRG   256         // candidate ranges
#define RPP   16          // pairs per range
#define RC    32          // cands per range
#define STEPS 11          // NN/gate scan iterations (STEPLIM + 1)
#define TOLV  1e-4

#define PADP(p) ((p) + ((p) >> 4))     // +1 slot per 16 pairs
#define SP_SZ (NPAIR + NPAIR/16)       // 4352 float4 slots per array

typedef float f32x2 __attribute__((ext_vector_type(2)));

// ---- ws layout (bytes) ----
#define WS_PXY    0        // float4[4096]    ->  65536
#define WS_PZW    65536    // float4[4096]    -> 131072
#define WS_TEMPPC 131072   // float [24576]   -> 229376
#define WS_BPA    229376   // double[256*16]  -> 262144
#define WS_BPB    262144   // double[256*16]  -> 294912
#define WS_ERRH   294912   // double[16]      -> 295040
#define WS_DONEH  295040   // int[16]

// ===========================================================================
// f32 Kabsch via Jacobi eigendecomposition of H^T H (reference SVD is f32).
// Proven trajectory-exact r7-r10 (absmax 0.0).
// ===========================================================================
__device__ void kabsch3f(const float H[3][3], const float c1[3], const float c2[3],
                         float R[3][3], float t[3]) {
    float A[3][3];
    for (int i = 0; i < 3; ++i)
        for (int j = 0; j < 3; ++j) {
            float sacc = 0.0f;
            for (int k = 0; k < 3; ++k) sacc += H[k][i] * H[k][j];
            A[i][j] = sacc;
        }
    float V[3][3] = {{1,0,0},{0,1,0},{0,0,1}};
    for (int sweep = 0; sweep < 6; ++sweep) {
        const int PQ[3][2] = {{0,1},{0,2},{1,2}};
        for (int mm = 0; mm < 3; ++mm) {
            int p = PQ[mm][0], q = PQ[mm][1];
            float apq = A[p][q];
            if (fabsf(apq) < 1e-30f) continue;
            float app = A[p][p], aqq = A[q][q];
            float tau = (aqq - app) / (2.0f * apq);
            float tt = (tau >= 0.0f) ? 1.0f / (tau + sqrtf(1.0f + tau*tau))
                                     : 1.0f / (tau - sqrtf(1.0f + tau*tau));
            float c = 1.0f / sqrtf(1.0f + tt*tt), s = tt * c;
            A[p][p] = app - tt * apq;
            A[q][q] = aqq + tt * apq;
            A[p][q] = 0.0f; A[q][p] = 0.0f;
            int k = 3 - p - q;
            float akp = A[k][p], akq = A[k][q];
            A[k][p] = c*akp - s*akq; A[p][k] = A[k][p];
            A[k][q] = s*akp + c*akq; A[q][k] = A[k][q];
            for (int r = 0; r < 3; ++r) {
                float vp = V[r][p], vq = V[r][q];
                V[r][p] = c*vp - s*vq;
                V[r][q] = s*vp + c*vq;
            }
        }
    }
    float lam[3] = {A[0][0], A[1][1], A[2][2]};
    int ord[3] = {0,1,2};
    for (int i = 0; i < 2; ++i)
        for (int j = i+1; j < 3; ++j)
            if (lam[ord[j]] > lam[ord[i]]) { int tmp = ord[i]; ord[i] = ord[j]; ord[j] = tmp; }
    float v0[3] = {V[0][ord[0]], V[1][ord[0]], V[2][ord[0]]};
    float v1[3] = {V[0][ord[1]], V[1][ord[1]], V[2][ord[1]]};
    float v2[3] = {V[0][ord[2]], V[1][ord[2]], V[2][ord[2]]};

    float u0[3], u1[3], hv2[3];
    for (int i = 0; i < 3; ++i) u0[i] = H[i][0]*v0[0] + H[i][1]*v0[1] + H[i][2]*v0[2];
    float n0 = sqrtf(u0[0]*u0[0] + u0[1]*u0[1] + u0[2]*u0[2]);
    n0 = fmaxf(n0, 1e-30f);
    for (int i = 0; i < 3; ++i) u0[i] /= n0;

    for (int i = 0; i < 3; ++i) u1[i] = H[i][0]*v1[0] + H[i][1]*v1[1] + H[i][2]*v1[2];
    float d01 = u1[0]*u0[0] + u1[1]*u0[1] + u1[2]*u0[2];
    for (int i = 0; i < 3; ++i) u1[i] -= d01 * u0[i];
    float n1 = sqrtf(u1[0]*u1[0] + u1[1]*u1[1] + u1[2]*u1[2]);
    n1 = fmaxf(n1, 1e-30f);
    for (int i = 0; i < 3; ++i) u1[i] /= n1;

    float u2[3] = {u0[1]*u1[2] - u0[2]*u1[1],
                   u0[2]*u1[0] - u0[0]*u1[2],
                   u0[0]*u1[1] - u0[1]*u1[0]};
    for (int i = 0; i < 3; ++i) hv2[i] = H[i][0]*v2[0] + H[i][1]*v2[1] + H[i][2]*v2[2];
    if (hv2[0]*u2[0] + hv2[1]*u2[1] + hv2[2]*u2[2] < 0.0f) {
        v2[0] = -v2[0]; v2[1] = -v2[1]; v2[2] = -v2[2];
    }
    float cx = v1[1]*v2[2] - v1[2]*v2[1];
    float cy = v1[2]*v2[0] - v1[0]*v2[2];
    float cz = v1[0]*v2[1] - v1[1]*v2[0];
    float detV = v0[0]*cx + v0[1]*cy + v0[2]*cz;
    float dsg = (detV < 0.0f) ? -1.0f : 1.0f;

    for (int i = 0; i < 3; ++i)
        for (int j = 0; j < 3; ++j)
            R[i][j] = v0[i]*u0[j] + v1[i]*u1[j] + dsg * v2[i]*u2[j];
    for (int i = 0; i < 3; ++i)
        t[i] = c2[i] - (R[i][0]*c1[0] + R[i][1]*c1[1] + R[i][2]*c1[2]);
}

__device__ __forceinline__ void build_Hf(const double s[16], float c1[3], float c2[3],
                                         float H[3][3]) {
    const double Nn = (double)N_PTS;
    double c1d[3] = {s[1]/Nn, s[2]/Nn, s[3]/Nn};
    double c2d[3] = {s[4]/Nn, s[5]/Nn, s[6]/Nn};
    for (int i = 0; i < 3; ++i) { c1[i] = (float)c1d[i]; c2[i] = (float)c2d[i]; }
    for (int i = 0; i < 3; ++i)
        for (int j = 0; j < 3; ++j)
            H[i][j] = (float)(s[7 + 3*i + j] - Nn * c1d[i] * c2d[j]);
}

// packed dual-FMA: ALL operands are 64-bit VGPR pairs (VOP3P requirement).
// IEEE fma per half -> bit-identical to scalar fmaf chain in same order.
__device__ __forceinline__ f32x2 pkfma(f32x2 a, f32x2 b, f32x2 c) {
    f32x2 d;
    asm("v_pk_fma_f32 %0, %1, %2, %3" : "=v"(d) : "v"(a), "v"(b), "v"(c));
    return d;
}

// ===========================================================================
// One ICP iteration per dispatch (it = 0..STEPS-1). NT=1024, 1 block/CU.
// Staging starts at instruction 0; wave 0 folds latch + gate + f32 Kabsch.
// Scan: packed f32 (2 cands per pk_fma), value-only, exact rescan recovery.
// ===========================================================================
__global__ __launch_bounds__(NT, 4) void icp_scan(
    const float* __restrict__ p1, const float* __restrict__ p2,
    float4* __restrict__ pXY, float4* __restrict__ pZW,
    float* __restrict__ temppc,
    const double* __restrict__ bp_prev, double* __restrict__ bp_cur,
    double* __restrict__ err_hist, int* __restrict__ done_hist, int it)
{
    __shared__ float4 sXY[SP_SZ];        // 69632 B  {x0,x1,y0,y1}
    __shared__ float4 sZW[SP_SZ];        // 69632 B  {z0,z1,w0,w1}
    __shared__ float4 sQ[QPB];
    __shared__ float  sWmin[16][QPT];
    __shared__ int    sWin[QPB];
    __shared__ float  sRt[12];
    __shared__ int    sDone;
    const int tid = threadIdx.x, bid = blockIdx.x;

    if (tid < QPB) sWin[tid] = 0x7fffffff;

    // ---- candidate staging: issues immediately, 4 pairs/thread ----
    if (it == 0) {
        #pragma unroll
        for (int k = 0; k < 4; ++k) {
            int p = tid + NT*k;
            float x0 = p2[6*p],   y0 = p2[6*p+1], z0 = p2[6*p+2];
            float x1 = p2[6*p+3], y1 = p2[6*p+4], z1 = p2[6*p+5];
            sXY[PADP(p)] = make_float4(x0, x1, y0, y1);
            sZW[PADP(p)] = make_float4(z0, z1,
                                       x0*x0 + y0*y0 + z0*z0,
                                       x1*x1 + y1*y1 + z1*z1);
        }
        if (tid == 0) {
            sDone = 0;
            if (bid == 0) { err_hist[0] = __builtin_inf(); done_hist[0] = 0; }
        }
    } else {
        #pragma unroll
        for (int k = 0; k < 4; ++k) {
            int p = tid + NT*k;
            sXY[PADP(p)] = pXY[p];
            sZW[PADP(p)] = pZW[p];
        }
        // wave 0: latch + gate reduce (fixed order) + f32 Kabsch
        if (tid < 64) {
            const int latched = done_hist[it-1];
            double sv[16];
            if (!latched) {
                #pragma unroll
                for (int k = 0; k < 16; ++k) sv[k] = 0.0;
                #pragma unroll
                for (int jj = 0; jj < 4; ++jj) {
                    const double* row = bp_prev + (tid + 64*jj)*16;
                    #pragma unroll
                    for (int k = 0; k < 16; ++k) sv[k] += row[k];
                }
                #pragma unroll
                for (int off = 1; off < 64; off <<= 1) {
                    #pragma unroll
                    for (int k = 0; k < 16; ++k) sv[k] += __shfl_xor(sv[k], off, 64);
                }
            }
            if (tid == 0) {
                if (latched) {
                    if (bid == 0) { done_hist[it] = 1; err_hist[it] = err_hist[it-1]; }
                    sDone = 1;
                } else {
                    double errnew = sv[0] / (double)N_PTS;
                    double err = err_hist[it-1];
                    double rel = fabs((errnew - err) / err);  // nan when err=inf -> false
                    int nd = (rel < TOLV) ? 1 : 0;
                    if (bid == 0) { done_hist[it] = nd; err_hist[it] = nd ? err : errnew; }
                    sDone = nd;
                    if (!nd) {
                        float c1[3], c2[3], H[3][3], Rm[3][3], tv[3];
                        build_Hf(sv, c1, c2, H);
                        kabsch3f(H, c1, c2, Rm, tv);
                        #pragma unroll
                        for (int i = 0; i < 3; ++i) {
                            sRt[3*i]   = Rm[i][0];
                            sRt[3*i+1] = Rm[i][1];
                            sRt[3*i+2] = Rm[i][2];
                            sRt[9+i]   = tv[i];
                        }
                    }
                }
            }
        }
    }
    __syncthreads();
    if (it > 0 && sDone) return;   // latched or freshly converged: frozen

    // publish packed pair arrays once (block 0 only)
    if (it == 0 && bid == 0) {
        #pragma unroll
        for (int k = 0; k < 4; ++k) {
            int p = tid + NT*k;
            pXY[p] = sXY[PADP(p)];
            pZW[p] = sZW[PADP(p)];
        }
    }

    // ---- own query coords: load, (transform), store, share ----
    if (tid < QPB) {
        int q = bid*QPB + tid;
        float x, y, z;
        if (it == 0) {
            x = p1[3*q]; y = p1[3*q+1]; z = p1[3*q+2];
        } else {
            float ox = temppc[3*q], oy = temppc[3*q+1], oz = temppc[3*q+2];
            x = fmaf(sRt[0], ox, fmaf(sRt[1], oy, fmaf(sRt[2], oz, sRt[9])));
            y = fmaf(sRt[3], ox, fmaf(sRt[4], oy, fmaf(sRt[5], oz, sRt[10])));
            z = fmaf(sRt[6], ox, fmaf(sRt[7], oy, fmaf(sRt[8], oz, sRt[11])));
        }
        temppc[3*q] = x; temppc[3*q+1] = y; temppc[3*q+2] = z;
        sQ[tid] = make_float4(x, y, z, x*x + y*y + z*z);
    }
    __syncthreads();

    // ---- NN scan: group g (8 queries) x range r (16 pairs), packed f32 ----
    const int g = tid >> 8;          // 0..3
    const int r = tid & 255;         // 0..255
    f32x2 qx2[QPT], qy2[QPT], qz2[QPT];
    #pragma unroll
    for (int k = 0; k < QPT; ++k) {
        float4 a = sQ[QPT*g + k];
        float mx = -2.f*a.x, my = -2.f*a.y, mz = -2.f*a.z;
        qx2[k].x = mx; qx2[k].y = mx;
        qy2[k].x = my; qy2[k].y = my;
        qz2[k].x = mz; qz2[k].y = mz;
    }
    f32x2 tmin2[QPT];
    #pragma unroll
    for (int k = 0; k < QPT; ++k) { tmin2[k].x = FLT_MAX; tmin2[k].y = FLT_MAX; }
    const int base = 17*r;           // PADP(16*r): 16 contiguous padded slots

#define PROCP(XY, ZW)                                                   \
    {                                                                   \
        f32x2 sx2 = { (XY).x, (XY).y };                                 \
        f32x2 sy2 = { (XY).z, (XY).w };                                 \
        f32x2 sz2 = { (ZW).x, (ZW).y };                                 \
        f32x2 sw2 = { (ZW).z, (ZW).w };                                 \
        _Pragma("unroll")                                               \
        for (int k = 0; k < QPT; ++k) {                                 \
            f32x2 t = pkfma(qx2[k], sx2, sw2);                          \
            t = pkfma(qy2[k], sy2, t);                                  \
            t = pkfma(qz2[k], sz2, t);                                  \
            tmin2[k].x = fminf(tmin2[k].x, t.x);                        \
            tmin2[k].y = fminf(tmin2[k].y, t.y);                        \
        }                                                               \
    }

    float4 xy = sXY[base], zw = sZW[base];
    #pragma unroll 5
    for (int j = 0; j < RPP - 1; ++j) {
        float4 nxy = sXY[base + j + 1], nzw = sZW[base + j + 1];
        PROCP(xy, zw);
        xy = nxy; zw = nzw;
    }
    PROCP(xy, zw);
#undef PROCP

    float tmin[QPT], omin[QPT];
    #pragma unroll
    for (int k = 0; k < QPT; ++k) {
        tmin[k] = fminf(tmin2[k].x, tmin2[k].y);
        omin[k] = tmin[k];
    }
    #pragma unroll
    for (int off = 1; off < 64; off <<= 1) {
        #pragma unroll
        for (int k = 0; k < QPT; ++k)
            tmin[k] = fminf(tmin[k], __shfl_xor(tmin[k], off, 64));
    }
    const int w = tid >> 6;          // wave 0..15; group g = w>>2
    if ((tid & 63) == 0) {
        #pragma unroll
        for (int k = 0; k < QPT; ++k) sWmin[w][k] = tmin[k];
    }
    __syncthreads();

    // winner range per query: smallest r achieving the global min
    #pragma unroll
    for (int k = 0; k < QPT; ++k) {
        float gm = fminf(fminf(sWmin[4*g][k],   sWmin[4*g+1][k]),
                         fminf(sWmin[4*g+2][k], sWmin[4*g+3][k]));
        if (omin[k] == gm) atomicMin(&sWin[QPT*g + k], r);
    }
    __syncthreads();

    // ---- finisher: rescan winning range (first-index) + block partials ----
    if (tid < 64) {
        double vals[16];
        if (tid < 32) {
            int q = tid, g2 = q >> 3, k2 = q & 7;
            float gm = fminf(fminf(sWmin[4*g2][k2],   sWmin[4*g2+1][k2]),
                             fminf(sWmin[4*g2+2][k2], sWmin[4*g2+3][k2]));
            int rw = sWin[q];
            float4 a4 = sQ[q];
            float mx = -2.f*a4.x, my = -2.f*a4.y, mz = -2.f*a4.z;
            int bix = -1;
            float bx = 0.f, by = 0.f, bz = 0.f;
            const int pb = 17*rw;
            #pragma unroll 8
            for (int j = 0; j < RC; ++j) {
                int pj = j >> 1, h = j & 1;
                float4 cxy = sXY[pb + pj];
                float4 czw = sZW[pb + pj];
                float sx = h ? cxy.y : cxy.x;
                float sy = h ? cxy.w : cxy.z;
                float sz = h ? czw.y : czw.x;
                float sw = h ? czw.w : czw.z;
                float v = fmaf(mx, sx, sw);
                v = fmaf(my, sy, v);
                v = fmaf(mz, sz, v);
                if (v == gm && bix < 0) { bix = RC*rw + j; bx = sx; by = sy; bz = sz; }
            }
            float d2 = fmaxf(gm + a4.w, 0.0f);
            float dmin = sqrtf(d2);
            vals[0] = (double)dmin;
            vals[1] = (double)a4.x; vals[2] = (double)a4.y; vals[3] = (double)a4.z;
            vals[4] = (double)bx;   vals[5] = (double)by;   vals[6] = (double)bz;
            vals[7]  = (double)a4.x*bx; vals[8]  = (double)a4.x*by; vals[9]  = (double)a4.x*bz;
            vals[10] = (double)a4.y*bx; vals[11] = (double)a4.y*by; vals[12] = (double)a4.y*bz;
            vals[13] = (double)a4.z*bx; vals[14] = (double)a4.z*by; vals[15] = (double)a4.z*bz;
        } else {
            #pragma unroll
            for (int k = 0; k < 16; ++k) vals[k] = 0.0;
        }
        #pragma unroll
        for (int off = 1; off < 32; off <<= 1) {
            #pragma unroll
            for (int k = 0; k < 16; ++k) vals[k] += __shfl_xor(vals[k], off, 64);
        }
        if (tid == 0) {
            double* d = bp_cur + bid*16;
            #pragma unroll
            for (int k = 0; k < 16; ++k) d[k] = vals[k];
        }
    }
}

// ===========================================================================
// Fused final dispatch (1 block): gate of step STEPS-1 + (optional) transform
// + whole-cloud final fit + Kabsch -> out. (r9/r10-proven)
// ===========================================================================
#define FNT 512
__global__ __launch_bounds__(FNT) void icp_final(
    const float* __restrict__ p1, const float* __restrict__ temppc,
    const double* __restrict__ bp,
    const double* __restrict__ err_hist, const int* __restrict__ done_hist,
    float* __restrict__ out)
{
    __shared__ float  sRt[12];
    __shared__ int    sDone;
    __shared__ double sred[8][16];
    const int tid = threadIdx.x;

    if (tid < 64) {
        if (done_hist[STEPS-1]) {
            if (tid == 0) sDone = 1;
        } else {
            double sv[16];
            #pragma unroll
            for (int k = 0; k < 16; ++k) sv[k] = 0.0;
            #pragma unroll
            for (int jj = 0; jj < 4; ++jj) {
                const double* row = bp + (tid + 64*jj)*16;
                #pragma unroll
                for (int k = 0; k < 16; ++k) sv[k] += row[k];
            }
            #pragma unroll
            for (int off = 1; off < 64; off <<= 1) {
                #pragma unroll
                for (int k = 0; k < 16; ++k) sv[k] += __shfl_xor(sv[k], off, 64);
            }
            if (tid == 0) {
                double errnew = sv[0] / (double)N_PTS;
                double err = err_hist[STEPS-1];
                double rel = fabs((errnew - err) / err);
                int nd = (rel < TOLV) ? 1 : 0;
                sDone = nd;
                if (!nd) {
                    float c1[3], c2[3], H[3][3], Rm[3][3], tv[3];
                    build_Hf(sv, c1, c2, H);
                    kabsch3f(H, c1, c2, Rm, tv);
                    #pragma unroll
                    for (int i = 0; i < 3; ++i) {
                        sRt[3*i]   = Rm[i][0];
                        sRt[3*i+1] = Rm[i][1];
                        sRt[3*i+2] = Rm[i][2];
                        sRt[9+i]   = tv[i];
                    }
                }
            }
        }
    }
    __syncthreads();
    const int dn = sDone;

    double acc[16];
    #pragma unroll
    for (int k = 0; k < 16; ++k) acc[k] = 0.0;
    for (int i = tid; i < N_PTS; i += FNT) {
        float ax = p1[3*i], ay = p1[3*i+1], az = p1[3*i+2];
        float bx = temppc[3*i], by = temppc[3*i+1], bz = temppc[3*i+2];
        if (!dn) {
            float nx = fmaf(sRt[0], bx, fmaf(sRt[1], by, fmaf(sRt[2], bz, sRt[9])));
            float ny = fmaf(sRt[3], bx, fmaf(sRt[4], by, fmaf(sRt[5], bz, sRt[10])));
            float nz = fmaf(sRt[6], bx, fmaf(sRt[7], by, fmaf(sRt[8], bz, sRt[11])));
            bx = nx; by = ny; bz = nz;
        }
        acc[1] += (double)ax;  acc[2] += (double)ay;  acc[3] += (double)az;
        acc[4] += (double)bx;  acc[5] += (double)by;  acc[6] += (double)bz;
        acc[7]  += (double)ax*bx; acc[8]  += (double)ax*by; acc[9]  += (double)ax*bz;
        acc[10] += (double)ay*bx; acc[11] += (double)ay*by; acc[12] += (double)ay*bz;
        acc[13] += (double)az*bx; acc[14] += (double)az*by; acc[15] += (double)az*bz;
    }
    #pragma unroll
    for (int off = 1; off < 64; off <<= 1) {
        #pragma unroll
        for (int k = 0; k < 16; ++k) acc[k] += __shfl_xor(acc[k], off, 64);
    }
    const int w = tid >> 6;
    if ((tid & 63) == 0) {
        #pragma unroll
        for (int k = 0; k < 16; ++k) sred[w][k] = acc[k];
    }
    __syncthreads();
    if (tid == 0) {
        double sv[16];
        #pragma unroll
        for (int k = 0; k < 16; ++k) {
            double s = 0.0;
            #pragma unroll
            for (int ww = 0; ww < 8; ++ww) s += sred[ww][k];
            sv[k] = s;
        }
        float c1[3], c2[3], H[3][3], Rm[3][3], tv[3];
        build_Hf(sv, c1, c2, H);
        kabsch3f(H, c1, c2, Rm, tv);
        #pragma unroll
        for (int i = 0; i < 3; ++i) {
            out[4*i + 0] = Rm[i][0];
            out[4*i + 1] = Rm[i][1];
            out[4*i + 2] = Rm[i][2];
            out[4*i + 3] = tv[i];
        }
    }
}

// ===========================================================================
extern "C" void kernel_launch(void* const* d_in, const int* in_sizes, int n_in,
                              void* d_out, int out_size, void* d_ws, size_t ws_size,
                              hipStream_t stream) {
    const float* p1 = (const float*)d_in[0];
    const float* p2 = (const float*)d_in[1];
    float* out = (float*)d_out;
    char* ws = (char*)d_ws;

    float4* pXY       = (float4*)(ws + WS_PXY);
    float4* pZW       = (float4*)(ws + WS_PZW);
    float*  temppc    = (float*) (ws + WS_TEMPPC);
    double* bpA       = (double*)(ws + WS_BPA);
    double* bpB       = (double*)(ws + WS_BPB);
    double* err_hist  = (double*)(ws + WS_ERRH);
    int*    done_hist = (int*)   (ws + WS_DONEH);

    for (int it = 0; it < STEPS; ++it) {
        double* cur  = (it & 1) ? bpB : bpA;
        double* prev = (it & 1) ? bpA : bpB;
        icp_scan<<<NB, NT, 0, stream>>>(p1, p2, pXY, pZW, temppc, prev, cur,
                                        err_hist, done_hist, it);
    }
    // STEPS-1 = 10 (even) -> last scan wrote bpA
    icp_final<<<1, FNT, 0, stream>>>(p1, temppc, bpA, err_hist, done_hist, out);
}